// Round 7
// baseline (147.828 us; speedup 1.0000x reference)
//
#include <hip/hip_runtime.h>

#define R_DIM 2048
#define O_DIM 32
#define I_DIM 16
#define B_DIM 64
#define BB 32   // batch rows per block (2 MFMA m-tiles)

typedef _Float16 half8  __attribute__((ext_vector_type(8)));
typedef float    f32x4  __attribute__((ext_vector_type(4)));

struct SplitH { half8 h1, h2; };

// 2-way fp16 split of 8 consecutive fp32 via HW packed-cvt (RTZ):
// x = h1 + h2 + O(2^-22 * x).
__device__ __forceinline__ SplitH splitf16x8(const float* __restrict__ p) {
    float f[8];
    *(float4*)(f)     = *(const float4*)(p);
    *(float4*)(f + 4) = *(const float4*)(p + 4);
    SplitH r;
    #pragma unroll
    for (int j = 0; j < 4; ++j) {
        const auto a = __builtin_amdgcn_cvt_pkrtz(f[2*j], f[2*j+1]);   // __fp16 x2
        const float r0 = f[2*j]     - (float)a[0];
        const float r1 = f[2*j + 1] - (float)a[1];
        const auto c = __builtin_amdgcn_cvt_pkrtz(r0, r1);
        r.h1[2*j] = (_Float16)a[0]; r.h1[2*j+1] = (_Float16)a[1];
        r.h2[2*j] = (_Float16)c[0]; r.h2[2*j+1] = (_Float16)c[1];
    }
    return r;
}

// DPP 16-lane (row) all-reduce sum — pure VALU pipe, no DS traffic.
template<int CTRL>
__device__ __forceinline__ float dpp_mv(float v) {
    int t = __builtin_amdgcn_update_dpp(0, __float_as_int(v), CTRL, 0xf, 0xf, true);
    return __int_as_float(t);
}
__device__ __forceinline__ float row16_sum(float v) {
    v += dpp_mv<0xB1>(v);    // quad_perm xor1
    v += dpp_mv<0x4E>(v);    // quad_perm xor2
    v += dpp_mv<0x124>(v);   // row_ror:4
    v += dpp_mv<0x128>(v);   // row_ror:8
    return v;
}

// XOR bank swizzle: phase-1 C-scatter and phase-2 c-major reads both land at
// the structural LDS minimum (2-way write aliasing = free per m136).
__device__ __forceinline__ int swaddr(int b, int col) {
    return b * 512 + (col ^ (((b ^ (b >> 2)) & 3) << 3));
}

// Block: 512 threads = 8 waves; one (r, 32-batch slice); 64 KB LDS, 2 blocks/CU.
// Phase 1: u_hat[32b x 512n] via 3-term fp16-split MFMA. Wave w owns n-tiles
//   4w..4w+3; each W-tile split ONCE, reused for both m-tiles (b 0-15, 16-31).
// Phase 2 (barrier-free, all 512 threads): thread=(b=tid>>4, j=tid&15) owns
//   o={2j,2j+1}; softmax redundant per-thread; reductions via DPP row16_sum.
__global__ __launch_bounds__(512, 4)
void capsule_routing_kernel(const float* __restrict__ x,
                            const float* __restrict__ W,
                            float* __restrict__ out) {
    __shared__ float u_lds[BB * 512];   // 64 KB, swizzled

    const int tid = threadIdx.x;
    const int bid = blockIdx.x;
    const int r   = bid >> 1;
    const int b0  = (bid & 1) * BB;

    // ---------------- Phase 1: fp16-split MFMA u_hat ----------------
    {
        const int lane = tid & 63;
        const int w    = tid >> 6;     // wave 0..7 -> n-tiles 4w..4w+3
        const int q    = lane >> 4;    // k-quad (2,3 = zero pad)
        const int np   = lane & 15;    // m (batch) for A / n-col for B

        const half8 z8 = {0,0,0,0,0,0,0,0};
        SplitH as[2];
        #pragma unroll
        for (int mt = 0; mt < 2; ++mt) {
            as[mt].h1 = z8; as[mt].h2 = z8;
            if (q < 2)
                as[mt] = splitf16x8(x + ((size_t)(b0 + mt * 16 + np) * R_DIM + r) * I_DIM + q * 8);
        }

        const f32x4 zero4 = {0.f, 0.f, 0.f, 0.f};
        #pragma unroll
        for (int t = 0; t < 4; ++t) {
            const int ntile = w * 4 + t;
            SplitH bs; bs.h1 = z8; bs.h2 = z8;
            if (q < 2)
                bs = splitf16x8(W + ((size_t)r * 512 + ntile * 16 + np) * I_DIM + q * 8);

            #pragma unroll
            for (int mt = 0; mt < 2; ++mt) {
                f32x4 a = __builtin_amdgcn_mfma_f32_16x16x32_f16(as[mt].h2, bs.h1, zero4, 0, 0, 0);
                a = __builtin_amdgcn_mfma_f32_16x16x32_f16(as[mt].h1, bs.h2, a, 0, 0, 0);
                a = __builtin_amdgcn_mfma_f32_16x16x32_f16(as[mt].h1, bs.h1, a, 0, 0, 0);
                const int col = ntile * 16 + np;
                #pragma unroll
                for (int reg = 0; reg < 4; ++reg)
                    u_lds[swaddr(mt * 16 + q * 4 + reg, col)] = a[reg];
            }
        }
    }
    __syncthreads();

    // ---------------- Phase 2: dynamic routing (all 512 threads) ----------------
    {
        const int b = tid >> 4;    // 0..31 local batch
        const int j = tid & 15;    // o-pair index

        float u2[32];              // u_hat[b][c][o=2j,2j+1]
        #pragma unroll
        for (int c = 0; c < 16; ++c) {
            const float2 v2 = *(const float2*)&u_lds[swaddr(b, c * 32 + 2 * j)];
            u2[2 * c]     = v2.x;
            u2[2 * c + 1] = v2.y;
        }

        float bv[16];
        #pragma unroll
        for (int c = 0; c < 16; ++c) bv[c] = 0.0f;

        float s0 = 0.f, s1 = 0.f, g = 0.f;

        #pragma unroll
        for (int it = 0; it < 3; ++it) {
            if (it == 0) {
                s0 = 0.f; s1 = 0.f;
                #pragma unroll
                for (int c = 0; c < 16; ++c) { s0 += u2[2*c]; s1 += u2[2*c+1]; }
                s0 *= 0.0625f; s1 *= 0.0625f;
            } else {
                float m = bv[0];
                #pragma unroll
                for (int c = 1; c < 16; ++c) m = fmaxf(m, bv[c]);
                float Z = 0.f; s0 = 0.f; s1 = 0.f;
                #pragma unroll
                for (int c = 0; c < 16; ++c) {
                    const float e = __expf(bv[c] - m);
                    Z += e;
                    s0 = fmaf(e, u2[2*c],   s0);
                    s1 = fmaf(e, u2[2*c+1], s1);
                }
                const float rZ = __builtin_amdgcn_rcpf(Z);
                s0 *= rZ; s1 *= rZ;
            }

            // g = ||s|| / (1 + ||s||^2), norm over 32 o's (16 j-lanes x 2)
            const float nn = row16_sum(s0 * s0 + s1 * s1);
            g = sqrtf(nn) * __builtin_amdgcn_rcpf(1.0f + nn);

            if (it < 2) {
                #pragma unroll
                for (int c = 0; c < 16; ++c) {
                    const float t = row16_sum(fmaf(u2[2*c], s0, u2[2*c+1] * s1));
                    bv[c] = fmaf(g, t, bv[c]);
                }
            }
        }

        *(float2*)(out + ((size_t)(b0 + b) * R_DIM + r) * O_DIM + 2 * j)
            = make_float2(g * s0, g * s1);
    }
}

extern "C" void kernel_launch(void* const* d_in, const int* in_sizes, int n_in,
                              void* d_out, int out_size, void* d_ws, size_t ws_size,
                              hipStream_t stream) {
    const float* x   = (const float*)d_in[0];   // [64, 2048, 16]
    const float* W   = (const float*)d_in[1];   // [2048, 16, 32, 16]
    float*       out = (float*)d_out;           // [64, 2048, 32]

    dim3 grid(R_DIM * (B_DIM / BB));            // 4096 blocks
    dim3 block(512);
    hipLaunchKernelGGL(capsule_routing_kernel, grid, block, 0, stream, x, W, out);
}